// Round 1
// baseline (3269.773 us; speedup 1.0000x reference)
//
#include <hip/hip_runtime.h>
#include <hip/hip_bf16.h>

#define B_ 128
#define T_ 256
#define D_ 256
#define H_ 1024
#define C_ 1000
#define NKC 40   // K-chunks of 32 over K=1280 (first 32 from h, last 8 from x_t)

typedef __attribute__((ext_vector_type(8))) short short8;
typedef __attribute__((ext_vector_type(4))) float floatx4;

static __device__ __forceinline__ unsigned short f2bf(float f) {
  unsigned int u = __builtin_bit_cast(unsigned int, f);
  u += 0x7fffu + ((u >> 16) & 1u);
  return (unsigned short)(u >> 16);
}
static __device__ __forceinline__ float bf2f(unsigned short s) {
  unsigned int u = ((unsigned int)s) << 16;
  return __builtin_bit_cast(float, u);
}
static __device__ __forceinline__ float sigm(float z) {
  return 1.0f / (1.0f + __expf(-z));
}
static __device__ __forceinline__ float tanh_fast(float z) {
  z = fminf(fmaxf(z, -15.f), 15.f);
  float e = __expf(2.f * z);
  return (e - 1.f) / (e + 1.f);
}

// ---------------------------------------------------------------------------
// Pack the 8 weight matrices (4 gates x {W_h [1024x1024], W_x [256x1024]}) into
// bf16, laid out so a wave's B-fragment load is one coalesced dwordx4:
// Wp[jb][kc][g][lane][i]  (jb<64, kc<40, g<4, lane<64, i<8)
// value = W_all[k = kc*32 + (lane>>4)*8 + i][col j = jb*16 + (lane&15)] for gate g,
// where k<1024 -> W_gh etc., k>=1024 -> W_gx etc.
// ---------------------------------------------------------------------------
__global__ __launch_bounds__(256) void pack_w(
    const float* __restrict__ Wgx, const float* __restrict__ Wix,
    const float* __restrict__ Wfx, const float* __restrict__ Wox,
    const float* __restrict__ Wgh, const float* __restrict__ Wih,
    const float* __restrict__ Wfh, const float* __restrict__ Woh,
    unsigned short* __restrict__ Wp) {
  int t = blockIdx.x * blockDim.x + threadIdx.x;  // 655,360 threads
  int L = t & 63;
  int g = (t >> 6) & 3;
  int rest = t >> 8;        // jb*40 + kc
  int kc = rest % 40;
  int jb = rest / 40;
  int n = L & 15, q = L >> 4;
  int j = jb * 16 + n;
  const float* Wh = (g == 0) ? Wgh : (g == 1) ? Wih : (g == 2) ? Wfh : Woh;
  const float* Wx = (g == 0) ? Wgx : (g == 1) ? Wix : (g == 2) ? Wfx : Wox;
  int k0 = kc * 32 + q * 8;
  unsigned int w[4];
#pragma unroll
  for (int i = 0; i < 4; i++) {
    int ka = k0 + 2 * i, kb = k0 + 2 * i + 1;
    float fa = (ka < H_) ? Wh[(size_t)ka * H_ + j] : Wx[(size_t)(ka - H_) * H_ + j];
    float fb = (kb < H_) ? Wh[(size_t)kb * H_ + j] : Wx[(size_t)(kb - H_) * H_ + j];
    w[i] = (unsigned int)f2bf(fa) | ((unsigned int)f2bf(fb) << 16);
  }
  uint4 v = {w[0], w[1], w[2], w[3]};
  *((uint4*)(Wp + (size_t)t * 8)) = v;  // thread-contiguous 16B: perfect coalescing
}

// ---------------------------------------------------------------------------
// Pack x [B][T][D] fp32 -> xb bf16 in per-step A-fragment layout:
// xb[t][rt][kcx][lane][i]: value = x[b = rt*16 + (lane&15)][t][d = kcx*32 + (lane>>4)*8 + i]
// ---------------------------------------------------------------------------
__global__ __launch_bounds__(256) void pack_x(const float* __restrict__ x,
                                              unsigned short* __restrict__ xb) {
  int idx = blockIdx.x * blockDim.x + threadIdx.x;  // 1,048,576 threads
  int d8 = idx & 31;          // which 8-wide d group
  int tt = (idx >> 5) & 255;  // time step
  int b = idx >> 13;          // batch row
  const float* src = x + ((size_t)b * T_ + tt) * D_ + d8 * 8;  // 32B contiguous
  int rt = b >> 4, kcx = d8 >> 2, q = d8 & 3, m = b & 15;
  size_t dst = ((((size_t)tt * 8 + rt) * 8 + kcx) * 64 + (q * 16 + m)) * 8;
  unsigned int w[4];
#pragma unroll
  for (int i = 0; i < 4; i++) {
    float fa = src[2 * i], fb = src[2 * i + 1];
    w[i] = (unsigned int)f2bf(fa) | ((unsigned int)f2bf(fb) << 16);
  }
  uint4 v = {w[0], w[1], w[2], w[3]};
  *((uint4*)(xb + dst)) = v;
}

// ---------------------------------------------------------------------------
// Two-level grid barrier (persistent cooperative kernel, 256 blocks).
// cnt[0] = master; cnt[(1+s)*64] = shard s arrival counter (8 shards, padded).
// Monotonic generations: caller passes gen = 1, 2, 3, ...
// Arrival RMW carries RELEASE (flushes this block's dirty h lines via wbl2);
// polls are RELAXED (no repeated cache-inv); one ACQUIRE load on exit
// invalidates stale L1/L2 lines before the next step's h reads.
// ---------------------------------------------------------------------------
static __device__ __forceinline__ void gridbar(unsigned int* cnt, unsigned int gen) {
  __syncthreads();   // all block stores vmcnt-drained, xg reads done
  if (threadIdx.x == 0) {
    unsigned int shard = blockIdx.x & 7;
    unsigned int prev = __hip_atomic_fetch_add(&cnt[(1u + shard) * 64u], 1u,
                                               __ATOMIC_RELEASE, __HIP_MEMORY_SCOPE_AGENT);
    if (prev == gen * 32u - 1u) {  // last arriver of this shard this generation
      __hip_atomic_fetch_add(&cnt[0], 1u, __ATOMIC_RELEASE, __HIP_MEMORY_SCOPE_AGENT);
    }
    while (__hip_atomic_load(&cnt[0], __ATOMIC_RELAXED, __HIP_MEMORY_SCOPE_AGENT) < gen * 8u) {
      __builtin_amdgcn_s_sleep(1);
    }
    (void)__hip_atomic_load(&cnt[0], __ATOMIC_ACQUIRE, __HIP_MEMORY_SCOPE_AGENT);
  }
  __syncthreads();
}

// ---------------------------------------------------------------------------
// Persistent LSTM: all 256 time steps in ONE cooperative kernel.
// 256 blocks x 256 threads, 1 block/CU (LDS-bound). Block (jb, rtq) owns the
// 32-row x 16-col output slice for all 4 gates. Its 128 KB of recurrent
// weights live in LDS for the whole kernel (loaded once, vs 10 MB/step from
// L2 before). 4 waves = (rt01 x khalf): K=1280 split in half per wave so the
// block's h-fragment reads are 1x-redundant and each wave carries 4
// independent MFMA chains (one per gate). Cell state c lives in registers.
// One grid barrier per step (h_t -> h_{t+1} is all-to-all over H).
// ---------------------------------------------------------------------------
__global__ __launch_bounds__(256, 1) void lstm_all(
    unsigned short* __restrict__ hb0, unsigned short* __restrict__ hb1,
    const unsigned short* __restrict__ Wp, const unsigned short* __restrict__ xb,
    const float* __restrict__ bg, const float* __restrict__ bi,
    const float* __restrict__ bf_, const float* __restrict__ bo,
    unsigned int* __restrict__ cnt) {
  __shared__ unsigned short WL[32 * 4 * 64 * 8];  // 128 KB recurrent weights (kc 0..31)
  __shared__ float xg[2][4][32][17];              // 17 KB gate partials (kh, g, row, col) +pad
  __shared__ float bb[4][16];                     // biases for this jb

  const int tid = threadIdx.x;
  const int bid = blockIdx.x;
  const int jb = bid >> 2, rtq = bid & 3;
  const int w = tid >> 6, lane = tid & 63;
  const int rt01 = w & 1, kh = w >> 1;
  const int rt = rtq * 2 + rt01;

  // ---- one-time: recurrent weights -> LDS (linear 128 KB copy, coalesced)
  {
    const uint4* src = (const uint4*)(Wp + (size_t)jb * (40 * 4 * 64 * 8));
    uint4* dst = (uint4*)WL;
#pragma unroll
    for (int i = 0; i < 32; i++) dst[i * 256 + tid] = src[i * 256 + tid];
  }
  if (tid < 64) {
    int g = tid >> 4, n = tid & 15;
    const float* bs = (g == 0) ? bg : (g == 1) ? bi : (g == 2) ? bf_ : bo;
    bb[g][n] = bs[jb * 16 + n];
  }
  // ---- zero-init this block's exclusive slice of h0 (fragment layout)
  {
    int rr = tid >> 3;
    int n0 = (tid & 7) * 2;
    int r = rtq * 32 + rr;
    int rt_r = r >> 4, m = r & 15;
#pragma unroll
    for (int u = 0; u < 2; u++) {
      int j = jb * 16 + n0 + u;
      size_t dst = ((size_t)(rt_r * 32 + (j >> 5)) * 64 + (((j >> 3) & 3) * 16 + m)) * 8 + (j & 7);
      hb0[dst] = 0;
    }
  }
  float c0 = 0.f, c1 = 0.f;
  gridbar(cnt, 1);

  const short8* BpX = (const short8*)Wp + (size_t)jb * (40 * 4 * 64) + lane;  // x-part weights (L2-hot)
  const short8* BL = (const short8*)WL + (size_t)kh * 4096 + lane;            // LDS offsets < 64 KB
  const int kc0 = kh * 16;  // this wave's h-part K chunks:  [kc0, kc0+16)
  const int kx0 = kh * 4;   // this wave's x-part K chunks:  [kx0, kx0+4)

#pragma unroll 1
  for (int t = 0; t < 256; t++) {
    const unsigned short* hc = (t & 1) ? hb1 : hb0;
    unsigned short* hn = (t & 1) ? hb0 : hb1;
    const short8* Ah = (const short8*)hc + ((size_t)rt * 32 + kc0) * 64 + lane;
    const short8* Ax = (const short8*)xb + (((size_t)t * 8 + rt) * 8 + kx0) * 64 + lane;

    // ---- prefetch all A fragments (20 x 16B) and x-part B fragments (16 x 16B):
    // all loads in flight together; in-order vmcnt retire pipelines them.
    short8 areg[20];
#pragma unroll
    for (int i = 0; i < 16; i++) areg[i] = Ah[(size_t)i * 64];
#pragma unroll
    for (int i = 0; i < 4; i++) areg[16 + i] = Ax[(size_t)i * 64];
    short8 bx[4][4];
#pragma unroll
    for (int i = 0; i < 4; i++) {
      int kk = 32 + kx0 + i;
#pragma unroll
      for (int g = 0; g < 4; g++) bx[i][g] = BpX[(size_t)(kk * 4 + g) * 64];
    }

    floatx4 a0 = {0.f, 0.f, 0.f, 0.f};
    floatx4 a1 = a0, a2 = a0, a3 = a0;
    // ---- h-part: B from LDS, 4 independent gate chains
#pragma unroll
    for (int kc = 0; kc < 16; kc++) {
      short8 av = areg[kc];
      short8 b0 = BL[(size_t)(kc * 4 + 0) * 64];
      short8 b1v = BL[(size_t)(kc * 4 + 1) * 64];
      short8 b2 = BL[(size_t)(kc * 4 + 2) * 64];
      short8 b3 = BL[(size_t)(kc * 4 + 3) * 64];
      a0 = __builtin_amdgcn_mfma_f32_16x16x32_bf16(av, b0, a0, 0, 0, 0);
      a1 = __builtin_amdgcn_mfma_f32_16x16x32_bf16(av, b1v, a1, 0, 0, 0);
      a2 = __builtin_amdgcn_mfma_f32_16x16x32_bf16(av, b2, a2, 0, 0, 0);
      a3 = __builtin_amdgcn_mfma_f32_16x16x32_bf16(av, b3, a3, 0, 0, 0);
    }
    // ---- x-part: B from registers
#pragma unroll
    for (int i = 0; i < 4; i++) {
      short8 av = areg[16 + i];
      a0 = __builtin_amdgcn_mfma_f32_16x16x32_bf16(av, bx[i][0], a0, 0, 0, 0);
      a1 = __builtin_amdgcn_mfma_f32_16x16x32_bf16(av, bx[i][1], a1, 0, 0, 0);
      a2 = __builtin_amdgcn_mfma_f32_16x16x32_bf16(av, bx[i][2], a2, 0, 0, 0);
      a3 = __builtin_amdgcn_mfma_f32_16x16x32_bf16(av, bx[i][3], a3, 0, 0, 0);
    }

    // ---- gate partials -> LDS (C/D layout: col = lane&15, row = (lane>>4)*4+p)
    {
      int cl = lane & 15, q = lane >> 4;
#pragma unroll
      for (int p = 0; p < 4; p++) {
        int rrow = rt01 * 16 + q * 4 + p;
        xg[kh][0][rrow][cl] = a0[p];
        xg[kh][1][rrow][cl] = a1[p];
        xg[kh][2][rrow][cl] = a2[p];
        xg[kh][3][rrow][cl] = a3[p];
      }
    }
    __syncthreads();

    // ---- pointwise cell update: 2 cells/thread, c in registers
    {
      int rr = tid >> 3, n0 = (tid & 7) * 2;
      int r = rtq * 32 + rr;
      int rt_r = r >> 4, m = r & 15;
#pragma unroll
      for (int u = 0; u < 2; u++) {
        int n = n0 + u;
        float pg = xg[0][0][rr][n] + xg[1][0][rr][n] + bb[0][n];
        float pi_ = xg[0][1][rr][n] + xg[1][1][rr][n] + bb[1][n];
        float pf = xg[0][2][rr][n] + xg[1][2][rr][n] + bb[2][n];
        float po = xg[0][3][rr][n] + xg[1][3][rr][n] + bb[3][n];
        float gg = tanh_fast(pg);
        float ii = sigm(pi_);
        float ff = sigm(pf);
        float oo = sigm(po);
        float cold = u ? c1 : c0;
        float cn = gg * ii + cold * ff;
        if (u) c1 = cn; else c0 = cn;
        float hv = tanh_fast(cn) * oo;
        int j = jb * 16 + n;
        size_t dst = ((size_t)(rt_r * 32 + (j >> 5)) * 64 + (((j >> 3) & 3) * 16 + m)) * 8 + (j & 7);
        hn[dst] = f2bf(hv);
      }
    }
    gridbar(cnt, (unsigned int)t + 2u);
  }
}

// ---------------------------------------------------------------------------
// Final projection p = h_T @ W_ph + b_p and row-wise log_softmax.
// One block per batch row; h row staged to LDS from A-fragment layout.
// ---------------------------------------------------------------------------
__global__ __launch_bounds__(256) void final_proj(const unsigned short* __restrict__ hB,
                                                  const float* __restrict__ Wph,
                                                  const float* __restrict__ bp,
                                                  float* __restrict__ out) {
  __shared__ float hrow[H_];
  __shared__ float red[256];
  int row = blockIdx.x, tid = threadIdx.x;
  int rt = row >> 4, m = row & 15;
#pragma unroll
  for (int i = 0; i < 4; i++) {
    int k = tid * 4 + i;
    size_t idx = ((size_t)(rt * 32 + (k >> 5)) * 64 + (((k >> 3) & 3) * 16 + m)) * 8 + (k & 7);
    hrow[k] = bf2f(hB[idx]);
  }
  __syncthreads();

  int c3 = (tid + 768 < C_) ? (tid + 768) : (C_ - 1);  // clamp (only tid<232 valid)
  float a0 = 0.f, a1 = 0.f, a2 = 0.f, a3 = 0.f;
#pragma unroll 4
  for (int k = 0; k < H_; k++) {
    float hv = hrow[k];
    const float* wr = Wph + (size_t)k * C_;
    a0 += hv * wr[tid];
    a1 += hv * wr[tid + 256];
    a2 += hv * wr[tid + 512];
    a3 += hv * wr[c3];
  }
  a0 += bp[tid];
  a1 += bp[tid + 256];
  a2 += bp[tid + 512];
  a3 += bp[c3];

  bool v3 = (tid + 768 < C_);
  float mx = fmaxf(fmaxf(a0, a1), a2);
  if (v3) mx = fmaxf(mx, a3);
  red[tid] = mx;
  __syncthreads();
  for (int s = 128; s > 0; s >>= 1) {
    if (tid < s) red[tid] = fmaxf(red[tid], red[tid + s]);
    __syncthreads();
  }
  float M = red[0];
  __syncthreads();
  float se = __expf(a0 - M) + __expf(a1 - M) + __expf(a2 - M);
  if (v3) se += __expf(a3 - M);
  red[tid] = se;
  __syncthreads();
  for (int s = 128; s > 0; s >>= 1) {
    if (tid < s) red[tid] += red[tid + s];
    __syncthreads();
  }
  float lse = M + logf(red[0]);
  out[(size_t)row * C_ + tid] = a0 - lse;
  out[(size_t)row * C_ + tid + 256] = a1 - lse;
  out[(size_t)row * C_ + tid + 512] = a2 - lse;
  if (v3) out[(size_t)row * C_ + tid + 768] = a3 - lse;
}

extern "C" void kernel_launch(void* const* d_in, const int* in_sizes, int n_in,
                              void* d_out, int out_size, void* d_ws, size_t ws_size,
                              hipStream_t stream) {
  const float* x   = (const float*)d_in[0];
  const float* Wgx = (const float*)d_in[1];
  const float* Wix = (const float*)d_in[2];
  const float* Wfx = (const float*)d_in[3];
  const float* Wox = (const float*)d_in[4];
  const float* Wgh = (const float*)d_in[5];
  const float* Wih = (const float*)d_in[6];
  const float* Wfh = (const float*)d_in[7];
  const float* Woh = (const float*)d_in[8];
  const float* Wph = (const float*)d_in[9];
  const float* bg  = (const float*)d_in[10];
  const float* bi  = (const float*)d_in[11];
  const float* bf  = (const float*)d_in[12];
  const float* bo  = (const float*)d_in[13];
  const float* bp  = (const float*)d_in[14];

  char* ws = (char*)d_ws;
  unsigned short* Wp = (unsigned short*)ws;                 // 10,485,760 B
  size_t off = 10485760;
  unsigned short* xb = (unsigned short*)(ws + off); off += 16777216;  // 16 MB
  unsigned short* h0 = (unsigned short*)(ws + off); off += 262144;
  unsigned short* h1 = (unsigned short*)(ws + off); off += 262144;
  unsigned int* cnt = (unsigned int*)(ws + off); off += 4096;  // barrier counters

  hipMemsetAsync(cnt, 0, 4096, stream);  // reset barrier each launch/replay

  pack_w<<<2560, 256, 0, stream>>>(Wgx, Wix, Wfx, Wox, Wgh, Wih, Wfh, Woh, Wp);
  pack_x<<<4096, 256, 0, stream>>>(x, xb);

  void* args[] = {(void*)&h0, (void*)&h1, (void*)&Wp, (void*)&xb,
                  (void*)&bg, (void*)&bi, (void*)&bf, (void*)&bo, (void*)&cnt};
  hipError_t cerr = hipLaunchCooperativeKernel((void*)lstm_all, dim3(256), dim3(256),
                                               args, 0, stream);
  if (cerr != hipSuccess) {
    // Fallback: plain launch. 256 blocks with ~148 KB LDS each force 1 block/CU
    // on a 256-CU device, so the grid is co-resident in practice.
    lstm_all<<<256, 256, 0, stream>>>(h0, h1, Wp, xb, bg, bi, bf, bo, cnt);
  }

  // after 256 steps the final h is in h0
  final_proj<<<128, 256, 0, stream>>>(h0, Wph, bp, (float*)d_out);
}

// Round 2
// 1494.429 us; speedup vs baseline: 2.1880x; 2.1880x over previous
//
#include <hip/hip_runtime.h>
#include <hip/hip_bf16.h>

#define B_ 128
#define T_ 256
#define D_ 256
#define H_ 1024
#define C_ 1000

typedef __attribute__((ext_vector_type(8))) short short8;
typedef __attribute__((ext_vector_type(4))) float floatx4;

static __device__ __forceinline__ unsigned short f2bf(float f) {
  unsigned int u = __builtin_bit_cast(unsigned int, f);
  u += 0x7fffu + ((u >> 16) & 1u);
  return (unsigned short)(u >> 16);
}
static __device__ __forceinline__ float bf2f(unsigned short s) {
  unsigned int u = ((unsigned int)s) << 16;
  return __builtin_bit_cast(float, u);
}
static __device__ __forceinline__ float sigm(float z) {
  return 1.0f / (1.0f + __expf(-z));
}
static __device__ __forceinline__ float tanh_fast(float z) {
  z = fminf(fmaxf(z, -15.f), 15.f);
  float e = __expf(2.f * z);
  return (e - 1.f) / (e + 1.f);
}

// ---------------------------------------------------------------------------
// Pack the 8 weight matrices (4 gates x {W_h [1024x1024], W_x [256x1024]}) into
// bf16, laid out so a wave's B-fragment load is one coalesced dwordx4:
// Wp[jb][kc][g][lane][i]  (jb<64, kc<40, g<4, lane<64, i<8)
// ---------------------------------------------------------------------------
__global__ __launch_bounds__(256) void pack_w(
    const float* __restrict__ Wgx, const float* __restrict__ Wix,
    const float* __restrict__ Wfx, const float* __restrict__ Wox,
    const float* __restrict__ Wgh, const float* __restrict__ Wih,
    const float* __restrict__ Wfh, const float* __restrict__ Woh,
    unsigned short* __restrict__ Wp) {
  int t = blockIdx.x * blockDim.x + threadIdx.x;  // 655,360 threads
  int L = t & 63;
  int g = (t >> 6) & 3;
  int rest = t >> 8;        // jb*40 + kc
  int kc = rest % 40;
  int jb = rest / 40;
  int n = L & 15, q = L >> 4;
  int j = jb * 16 + n;
  const float* Wh = (g == 0) ? Wgh : (g == 1) ? Wih : (g == 2) ? Wfh : Woh;
  const float* Wx = (g == 0) ? Wgx : (g == 1) ? Wix : (g == 2) ? Wfx : Wox;
  int k0 = kc * 32 + q * 8;
  unsigned int w[4];
#pragma unroll
  for (int i = 0; i < 4; i++) {
    int ka = k0 + 2 * i, kb = k0 + 2 * i + 1;
    float fa = (ka < H_) ? Wh[(size_t)ka * H_ + j] : Wx[(size_t)(ka - H_) * H_ + j];
    float fb = (kb < H_) ? Wh[(size_t)kb * H_ + j] : Wx[(size_t)(kb - H_) * H_ + j];
    w[i] = (unsigned int)f2bf(fa) | ((unsigned int)f2bf(fb) << 16);
  }
  uint4 v = {w[0], w[1], w[2], w[3]};
  *((uint4*)(Wp + (size_t)t * 8)) = v;
}

// ---------------------------------------------------------------------------
// Pack x [B][T][D] fp32 -> xb bf16 in per-step A-fragment layout:
// xb[t][rt][kcx][lane][i]
// ---------------------------------------------------------------------------
__global__ __launch_bounds__(256) void pack_x(const float* __restrict__ x,
                                              unsigned short* __restrict__ xb) {
  int idx = blockIdx.x * blockDim.x + threadIdx.x;  // 1,048,576 threads
  int d8 = idx & 31;
  int tt = (idx >> 5) & 255;
  int b = idx >> 13;
  const float* src = x + ((size_t)b * T_ + tt) * D_ + d8 * 8;
  int rt = b >> 4, kcx = d8 >> 2, q = d8 & 3, m = b & 15;
  size_t dst = ((((size_t)tt * 8 + rt) * 8 + kcx) * 64 + (q * 16 + m)) * 8;
  unsigned int w[4];
#pragma unroll
  for (int i = 0; i < 4; i++) {
    float fa = src[2 * i], fb = src[2 * i + 1];
    w[i] = (unsigned int)f2bf(fa) | ((unsigned int)f2bf(fb) << 16);
  }
  uint4 v = {w[0], w[1], w[2], w[3]};
  *((uint4*)(xb + dst)) = v;
}

// ---------------------------------------------------------------------------
// Persistent LSTM, one cooperative kernel, 256 blocks x 256 threads.
// ALL cross-block data movement (h, barrier counters) uses relaxed AGENT-scope
// per-access atomics: stores write through to the coherence point (MALL),
// loads bypass the (non-coherent, per-XCD) L2. NO release/acquire fences in
// the loop -- R1 showed the cache-wide wbl2/inv fences were the ~12 us/step
// cost (MfmaUtil 4.6%, all idle). Ordering argument: __syncthreads drains
// vmcnt (stores complete at MALL) before the leader's arrival RMW issues;
// readers observe the counter at MALL strictly after, then load h at MALL.
// The barrier-wait window is filled with the x-part GEMM (h-independent).
// ---------------------------------------------------------------------------
__global__ __launch_bounds__(256, 1) void lstm_all(
    unsigned short* __restrict__ hb0, unsigned short* __restrict__ hb1,
    const unsigned short* __restrict__ Wp, const unsigned short* __restrict__ xb,
    const float* __restrict__ bg, const float* __restrict__ bi,
    const float* __restrict__ bf_, const float* __restrict__ bo,
    unsigned int* __restrict__ cnt) {
  __shared__ unsigned short WL[32 * 4 * 64 * 8];  // 128 KB recurrent weights
  __shared__ float xg[2][4][32][17];              // gate partials (kh, g, row, col)
  __shared__ float bb[4][16];

  const int tid = threadIdx.x;
  const int bid = blockIdx.x;
  const int jb = bid >> 2, rtq = bid & 3;
  const int w = tid >> 6, lane = tid & 63;
  const int rt01 = w & 1, kh = w >> 1;
  const int rt = rtq * 2 + rt01;
  const unsigned int shard = (unsigned int)(bid & 7);

  // ---- one-time: recurrent weights -> LDS (128 KB, coalesced)
  {
    const uint4* src = (const uint4*)(Wp + (size_t)jb * (40 * 4 * 64 * 8));
    uint4* dst = (uint4*)WL;
#pragma unroll
    for (int i = 0; i < 32; i++) dst[i * 256 + tid] = src[i * 256 + tid];
  }
  if (tid < 64) {
    int g = tid >> 4, n = tid & 15;
    const float* bs = (g == 0) ? bg : (g == 1) ? bi : (g == 2) ? bf_ : bo;
    bb[g][n] = bs[jb * 16 + n];
  }
  // ---- zero-init this block's slice of h0 (write-through so all XCDs see it)
  {
    int rr = tid >> 3, n0 = (tid & 7) * 2;
    int r = rtq * 32 + rr;
    int rt_r = r >> 4, m = r & 15;
    int j = jb * 16 + n0;
    size_t dst = ((size_t)(rt_r * 32 + (j >> 5)) * 64 + (((j >> 3) & 3) * 16 + m)) * 8 + (j & 7);
    __hip_atomic_store((unsigned int*)(hb0 + dst), 0u, __ATOMIC_RELAXED,
                       __HIP_MEMORY_SCOPE_AGENT);
  }
  float c0 = 0.f, c1 = 0.f;

  const short8* BpX = (const short8*)Wp + (size_t)jb * (40 * 4 * 64) + lane;
  const short8* BL = (const short8*)WL + (size_t)kh * 4096 + lane;
  const int kc0 = kh * 16;  // h-part K chunks [kc0, kc0+16)
  const int kx0 = kh * 4;   // x-part K chunks [kx0, kx0+4)

  // ---- x-part weights are time-invariant: hold in registers for all 256 steps
  short8 bxw[4][4];
#pragma unroll
  for (int i = 0; i < 4; i++)
#pragma unroll
    for (int g = 0; g < 4; g++)
      bxw[i][g] = BpX[(size_t)((32 + kx0 + i) * 4 + g) * 64];

  __syncthreads();  // drains vmcnt: h0 init stores are at MALL before arrival

#pragma unroll 1
  for (int t = 0; t < 256; t++) {
    const unsigned short* hc = (t & 1) ? hb1 : hb0;
    unsigned short* hn = (t & 1) ? hb0 : hb1;

    // ---- x-part A fragments for this step (L2-hot)
    const short8* Ax = (const short8*)xb + (((size_t)t * 8 + rt) * 8 + kx0) * 64 + lane;
    short8 ax[4];
#pragma unroll
    for (int i = 0; i < 4; i++) ax[i] = Ax[(size_t)i * 64];

    // ---- arrival for gen t+1: "my h_t stores are visible" (relaxed, no fence)
    if (tid == 0) {
      unsigned int gen = (unsigned int)t + 1u;
      unsigned int prev = __hip_atomic_fetch_add(&cnt[(1u + shard) * 32u], 1u,
                                                 __ATOMIC_RELAXED, __HIP_MEMORY_SCOPE_AGENT);
      if (prev == gen * 32u - 1u)  // last arriver of this shard -> cascade to master
        __hip_atomic_fetch_add(&cnt[0], 1u, __ATOMIC_RELAXED, __HIP_MEMORY_SCOPE_AGENT);
    }

    // ---- x-part GEMM fills the barrier-wait window (no h dependency)
    floatx4 a0 = {0.f, 0.f, 0.f, 0.f};
    floatx4 a1 = a0, a2 = a0, a3 = a0;
#pragma unroll
    for (int i = 0; i < 4; i++) {
      a0 = __builtin_amdgcn_mfma_f32_16x16x32_bf16(ax[i], bxw[i][0], a0, 0, 0, 0);
      a1 = __builtin_amdgcn_mfma_f32_16x16x32_bf16(ax[i], bxw[i][1], a1, 0, 0, 0);
      a2 = __builtin_amdgcn_mfma_f32_16x16x32_bf16(ax[i], bxw[i][2], a2, 0, 0, 0);
      a3 = __builtin_amdgcn_mfma_f32_16x16x32_bf16(ax[i], bxw[i][3], a3, 0, 0, 0);
    }

    // ---- wait: everyone has stored h_t
    if (tid == 0) {
      unsigned int tgt = ((unsigned int)t + 1u) * 8u;
      while (__hip_atomic_load(&cnt[0], __ATOMIC_RELAXED, __HIP_MEMORY_SCOPE_AGENT) < tgt)
        __builtin_amdgcn_s_sleep(1);
    }
    __syncthreads();
    asm volatile("" ::: "memory");  // no compiler motion of h loads above the poll

    // ---- h loads: relaxed agent (bypass stale L2, served at MALL)
    const unsigned short* Ahp = hc + ((size_t)(rt * 32 + kc0) * 64 + lane) * 8;
    unsigned long long hq[32];
#pragma unroll
    for (int i = 0; i < 16; i++) {
      hq[2 * i] = __hip_atomic_load((const unsigned long long*)(Ahp + (size_t)i * 512),
                                    __ATOMIC_RELAXED, __HIP_MEMORY_SCOPE_AGENT);
      hq[2 * i + 1] = __hip_atomic_load((const unsigned long long*)(Ahp + (size_t)i * 512 + 4),
                                        __ATOMIC_RELAXED, __HIP_MEMORY_SCOPE_AGENT);
    }

    // ---- h-part GEMM: B from LDS, 4 independent gate chains
#pragma unroll
    for (int kc = 0; kc < 16; kc++) {
      union { unsigned long long q[2]; short8 v; } u;
      u.q[0] = hq[2 * kc];
      u.q[1] = hq[2 * kc + 1];
      short8 av = u.v;
      short8 b0 = BL[(size_t)(kc * 4 + 0) * 64];
      short8 b1v = BL[(size_t)(kc * 4 + 1) * 64];
      short8 b2 = BL[(size_t)(kc * 4 + 2) * 64];
      short8 b3 = BL[(size_t)(kc * 4 + 3) * 64];
      a0 = __builtin_amdgcn_mfma_f32_16x16x32_bf16(av, b0, a0, 0, 0, 0);
      a1 = __builtin_amdgcn_mfma_f32_16x16x32_bf16(av, b1v, a1, 0, 0, 0);
      a2 = __builtin_amdgcn_mfma_f32_16x16x32_bf16(av, b2, a2, 0, 0, 0);
      a3 = __builtin_amdgcn_mfma_f32_16x16x32_bf16(av, b3, a3, 0, 0, 0);
    }

    // ---- gate partials -> LDS (C/D layout: col = lane&15, row = (lane>>4)*4+p)
    {
      int cl = lane & 15, q = lane >> 4;
#pragma unroll
      for (int p = 0; p < 4; p++) {
        int rrow = rt01 * 16 + q * 4 + p;
        xg[kh][0][rrow][cl] = a0[p];
        xg[kh][1][rrow][cl] = a1[p];
        xg[kh][2][rrow][cl] = a2[p];
        xg[kh][3][rrow][cl] = a3[p];
      }
    }
    __syncthreads();

    // ---- pointwise cell update: 2 adjacent cells/thread, packed 4-B h store
    {
      int rr = tid >> 3, n0 = (tid & 7) * 2;
      int r = rtq * 32 + rr;
      int rt_r = r >> 4, m = r & 15;
      unsigned int packed = 0;
#pragma unroll
      for (int u = 0; u < 2; u++) {
        int n = n0 + u;
        float pg = xg[0][0][rr][n] + xg[1][0][rr][n] + bb[0][n];
        float pi_ = xg[0][1][rr][n] + xg[1][1][rr][n] + bb[1][n];
        float pf = xg[0][2][rr][n] + xg[1][2][rr][n] + bb[2][n];
        float po = xg[0][3][rr][n] + xg[1][3][rr][n] + bb[3][n];
        float gg = tanh_fast(pg);
        float ii = sigm(pi_);
        float ff = sigm(pf);
        float oo = sigm(po);
        float cold = u ? c1 : c0;
        float cn = gg * ii + cold * ff;
        if (u) c1 = cn; else c0 = cn;
        float hv = tanh_fast(cn) * oo;
        packed |= ((unsigned int)f2bf(hv)) << (16 * u);
      }
      int j = jb * 16 + n0;
      size_t dst = ((size_t)(rt_r * 32 + (j >> 5)) * 64 + (((j >> 3) & 3) * 16 + m)) * 8 + (j & 7);
      __hip_atomic_store((unsigned int*)(hn + dst), packed, __ATOMIC_RELAXED,
                         __HIP_MEMORY_SCOPE_AGENT);
    }
    asm volatile("" ::: "memory");
    __syncthreads();  // drains vmcnt: h_{t+1} at MALL before next arrival
  }
}

// ---------------------------------------------------------------------------
// Final projection p = h_T @ W_ph + b_p and row-wise log_softmax.
// ---------------------------------------------------------------------------
__global__ __launch_bounds__(256) void final_proj(const unsigned short* __restrict__ hB,
                                                  const float* __restrict__ Wph,
                                                  const float* __restrict__ bp,
                                                  float* __restrict__ out) {
  __shared__ float hrow[H_];
  __shared__ float red[256];
  int row = blockIdx.x, tid = threadIdx.x;
  int rt = row >> 4, m = row & 15;
#pragma unroll
  for (int i = 0; i < 4; i++) {
    int k = tid * 4 + i;
    size_t idx = ((size_t)(rt * 32 + (k >> 5)) * 64 + (((k >> 3) & 3) * 16 + m)) * 8 + (k & 7);
    hrow[k] = bf2f(hB[idx]);
  }
  __syncthreads();

  int c3 = (tid + 768 < C_) ? (tid + 768) : (C_ - 1);
  float a0 = 0.f, a1 = 0.f, a2 = 0.f, a3 = 0.f;
#pragma unroll 4
  for (int k = 0; k < H_; k++) {
    float hv = hrow[k];
    const float* wr = Wph + (size_t)k * C_;
    a0 += hv * wr[tid];
    a1 += hv * wr[tid + 256];
    a2 += hv * wr[tid + 512];
    a3 += hv * wr[c3];
  }
  a0 += bp[tid];
  a1 += bp[tid + 256];
  a2 += bp[tid + 512];
  a3 += bp[c3];

  bool v3 = (tid + 768 < C_);
  float mx = fmaxf(fmaxf(a0, a1), a2);
  if (v3) mx = fmaxf(mx, a3);
  red[tid] = mx;
  __syncthreads();
  for (int s = 128; s > 0; s >>= 1) {
    if (tid < s) red[tid] = fmaxf(red[tid], red[tid + s]);
    __syncthreads();
  }
  float M = red[0];
  __syncthreads();
  float se = __expf(a0 - M) + __expf(a1 - M) + __expf(a2 - M);
  if (v3) se += __expf(a3 - M);
  red[tid] = se;
  __syncthreads();
  for (int s = 128; s > 0; s >>= 1) {
    if (tid < s) red[tid] += red[tid + s];
    __syncthreads();
  }
  float lse = M + logf(red[0]);
  out[(size_t)row * C_ + tid] = a0 - lse;
  out[(size_t)row * C_ + tid + 256] = a1 - lse;
  out[(size_t)row * C_ + tid + 512] = a2 - lse;
  if (v3) out[(size_t)row * C_ + tid + 768] = a3 - lse;
}

extern "C" void kernel_launch(void* const* d_in, const int* in_sizes, int n_in,
                              void* d_out, int out_size, void* d_ws, size_t ws_size,
                              hipStream_t stream) {
  const float* x   = (const float*)d_in[0];
  const float* Wgx = (const float*)d_in[1];
  const float* Wix = (const float*)d_in[2];
  const float* Wfx = (const float*)d_in[3];
  const float* Wox = (const float*)d_in[4];
  const float* Wgh = (const float*)d_in[5];
  const float* Wih = (const float*)d_in[6];
  const float* Wfh = (const float*)d_in[7];
  const float* Woh = (const float*)d_in[8];
  const float* Wph = (const float*)d_in[9];
  const float* bg  = (const float*)d_in[10];
  const float* bi  = (const float*)d_in[11];
  const float* bf  = (const float*)d_in[12];
  const float* bo  = (const float*)d_in[13];
  const float* bp  = (const float*)d_in[14];

  char* ws = (char*)d_ws;
  unsigned short* Wp = (unsigned short*)ws;                 // 10,485,760 B
  size_t off = 10485760;
  unsigned short* xb = (unsigned short*)(ws + off); off += 16777216;  // 16 MB
  unsigned short* h0 = (unsigned short*)(ws + off); off += 262144;
  unsigned short* h1 = (unsigned short*)(ws + off); off += 262144;
  unsigned int* cnt = (unsigned int*)(ws + off); off += 4096;

  hipMemsetAsync(cnt, 0, 4096, stream);  // reset barrier each launch/replay

  pack_w<<<2560, 256, 0, stream>>>(Wgx, Wix, Wfx, Wox, Wgh, Wih, Wfh, Woh, Wp);
  pack_x<<<4096, 256, 0, stream>>>(x, xb);

  void* args[] = {(void*)&h0, (void*)&h1, (void*)&Wp, (void*)&xb,
                  (void*)&bg, (void*)&bi, (void*)&bf, (void*)&bo, (void*)&cnt};
  hipError_t cerr = hipLaunchCooperativeKernel((void*)lstm_all, dim3(256), dim3(256),
                                               args, 0, stream);
  if (cerr != hipSuccess) {
    // Fallback: 256 blocks with ~146 KB LDS each force 1 block/CU -> co-resident
    lstm_all<<<256, 256, 0, stream>>>(h0, h1, Wp, xb, bg, bi, bf, bo, cnt);
  }

  final_proj<<<128, 256, 0, stream>>>(h0, Wph, bp, (float*)d_out);
}

// Round 3
// 1120.506 us; speedup vs baseline: 2.9181x; 1.3337x over previous
//
#include <hip/hip_runtime.h>
#include <hip/hip_bf16.h>

#define B_ 128
#define T_ 256
#define D_ 256
#define H_ 1024
#define C_ 1000

typedef __attribute__((ext_vector_type(8))) short short8;
typedef __attribute__((ext_vector_type(4))) float floatx4;

static __device__ __forceinline__ unsigned short f2bf(float f) {
  unsigned int u = __builtin_bit_cast(unsigned int, f);
  u += 0x7fffu + ((u >> 16) & 1u);
  return (unsigned short)(u >> 16);
}
static __device__ __forceinline__ float bf2f(unsigned short s) {
  unsigned int u = ((unsigned int)s) << 16;
  return __builtin_bit_cast(float, u);
}
static __device__ __forceinline__ float sigm(float z) {
  return 1.0f / (1.0f + __expf(-z));
}
static __device__ __forceinline__ float tanh_fast(float z) {
  z = fminf(fmaxf(z, -15.f), 15.f);
  float e = __expf(2.f * z);
  return (e - 1.f) / (e + 1.f);
}

// ---------------------------------------------------------------------------
// Fused pack kernel. Blocks [0,2560): pack_w -> Wp[jb][kc][g][lane][i].
// Blocks [2560,6656): pack_x -> xb[t][rt][kcx][lane][i].
// ---------------------------------------------------------------------------
__global__ __launch_bounds__(256) void pack_all(
    const float* __restrict__ Wgx, const float* __restrict__ Wix,
    const float* __restrict__ Wfx, const float* __restrict__ Wox,
    const float* __restrict__ Wgh, const float* __restrict__ Wih,
    const float* __restrict__ Wfh, const float* __restrict__ Woh,
    unsigned short* __restrict__ Wp,
    const float* __restrict__ x, unsigned short* __restrict__ xb) {
  int blk = blockIdx.x;
  if (blk < 2560) {
    int t = blk * 256 + threadIdx.x;  // 655,360 threads
    int L = t & 63;
    int g = (t >> 6) & 3;
    int rest = t >> 8;        // jb*40 + kc
    int kc = rest % 40;
    int jb = rest / 40;
    int n = L & 15, q = L >> 4;
    int j = jb * 16 + n;
    const float* Wh = (g == 0) ? Wgh : (g == 1) ? Wih : (g == 2) ? Wfh : Woh;
    const float* Wx = (g == 0) ? Wgx : (g == 1) ? Wix : (g == 2) ? Wfx : Wox;
    int k0 = kc * 32 + q * 8;
    unsigned int w[4];
#pragma unroll
    for (int i = 0; i < 4; i++) {
      int ka = k0 + 2 * i, kb = k0 + 2 * i + 1;
      float fa = (ka < H_) ? Wh[(size_t)ka * H_ + j] : Wx[(size_t)(ka - H_) * H_ + j];
      float fb = (kb < H_) ? Wh[(size_t)kb * H_ + j] : Wx[(size_t)(kb - H_) * H_ + j];
      w[i] = (unsigned int)f2bf(fa) | ((unsigned int)f2bf(fb) << 16);
    }
    uint4 v = {w[0], w[1], w[2], w[3]};
    *((uint4*)(Wp + (size_t)t * 8)) = v;
  } else {
    int idx = (blk - 2560) * 256 + threadIdx.x;  // 1,048,576 threads
    int d8 = idx & 31;
    int tt = (idx >> 5) & 255;
    int b = idx >> 13;
    const float* src = x + ((size_t)b * T_ + tt) * D_ + d8 * 8;
    int rt = b >> 4, kcx = d8 >> 2, q = d8 & 3, m = b & 15;
    size_t dst = ((((size_t)tt * 8 + rt) * 8 + kcx) * 64 + (q * 16 + m)) * 8;
    unsigned int w[4];
#pragma unroll
    for (int i = 0; i < 4; i++) {
      float fa = src[2 * i], fb = src[2 * i + 1];
      w[i] = (unsigned int)f2bf(fa) | ((unsigned int)f2bf(fb) << 16);
    }
    uint4 v = {w[0], w[1], w[2], w[3]};
    *((uint4*)(xb + dst)) = v;
  }
}

// ---------------------------------------------------------------------------
// Persistent LSTM, one cooperative kernel, 256 blocks x 256 threads.
// R3 barrier design: per-block FLAG STORES (no RMW serialization, no cascade)
// + 4 independent 64-block barriers (block (jb,rtq) consumes h rows of its
// own rtq-slice only, produced by the 64 blocks sharing rtq). One wave polls
// its group's 64 flags with a single per-lane load + __all. The x-part GEMM
// of step t+1 is computed inside the poll window. All cross-block data
// (h, flags) moves via relaxed AGENT-scope accesses (MALL-coherent, no
// cache-wide fences). Ordering: __syncthreads drains vmcnt (h stores ack'd
// at MALL) before the flag store issues; a consumer that observes the flag
// therefore observes the h data.
// ---------------------------------------------------------------------------
__global__ __launch_bounds__(256, 1) void lstm_all(
    unsigned short* __restrict__ hb0, unsigned short* __restrict__ hb1,
    const unsigned short* __restrict__ Wp, const unsigned short* __restrict__ xb,
    const float* __restrict__ bg, const float* __restrict__ bi,
    const float* __restrict__ bf_, const float* __restrict__ bo,
    unsigned int* __restrict__ fl) {
  __shared__ unsigned short WL[32 * 4 * 64 * 8];  // 128 KB recurrent weights
  __shared__ float xg[2][4][32][17];              // gate partials (kh, g, row, col)
  __shared__ float bb[4][16];

  const int tid = threadIdx.x;
  const int bid = blockIdx.x;
  const int jb = bid >> 2, rtq = bid & 3;
  const int w = tid >> 6, lane = tid & 63;
  const int rt01 = w & 1, kh = w >> 1;
  const int rt = rtq * 2 + rt01;
  const int grp = rtq * 64;  // this group's flag region

  // ---- one-time: recurrent weights -> LDS (128 KB, coalesced)
  {
    const uint4* src = (const uint4*)(Wp + (size_t)jb * (40 * 4 * 64 * 8));
    uint4* dst = (uint4*)WL;
#pragma unroll
    for (int i = 0; i < 32; i++) dst[i * 256 + tid] = src[i * 256 + tid];
  }
  if (tid < 64) {
    int g = tid >> 4, n = tid & 15;
    const float* bs = (g == 0) ? bg : (g == 1) ? bi : (g == 2) ? bf_ : bo;
    bb[g][n] = bs[jb * 16 + n];
  }
  // ---- zero-init this block's slice of h0 (write-through so all XCDs see it)
  {
    int rr = tid >> 3, n0 = (tid & 7) * 2;
    int r = rtq * 32 + rr;
    int rt_r = r >> 4, m = r & 15;
    int j = jb * 16 + n0;
    size_t dst = ((size_t)(rt_r * 32 + (j >> 5)) * 64 + (((j >> 3) & 3) * 16 + m)) * 8 + (j & 7);
    __hip_atomic_store((unsigned int*)(hb0 + dst), 0u, __ATOMIC_RELAXED,
                       __HIP_MEMORY_SCOPE_AGENT);
  }
  float c0 = 0.f, c1 = 0.f;

  const short8* BpX = (const short8*)Wp + (size_t)jb * (40 * 4 * 64) + lane;
  const short8* BL = (const short8*)WL + (size_t)kh * 4096 + lane;
  const int kc0 = kh * 16;  // h-part K chunks [kc0, kc0+16)
  const int kx0 = kh * 4;   // x-part K chunks [kx0, kx0+4)

  // ---- x-part weights are time-invariant: hold in registers for all 256 steps
  short8 bxw[4][4];
#pragma unroll
  for (int i = 0; i < 4; i++)
#pragma unroll
    for (int g = 0; g < 4; g++)
      bxw[i][g] = BpX[(size_t)((32 + kx0 + i) * 4 + g) * 64];

  __syncthreads();  // drains vmcnt: h0 init stores are at MALL before flag

  // ---- prologue arrival: "my h0 slice is visible" + x-GEMM for step 0
  if (tid == 0)
    __hip_atomic_store(&fl[grp + jb], 1u, __ATOMIC_RELAXED, __HIP_MEMORY_SCOPE_AGENT);

  floatx4 xa0 = {0.f, 0.f, 0.f, 0.f};
  floatx4 xa1 = xa0, xa2 = xa0, xa3 = xa0;
  {
    const short8* Ax = (const short8*)xb + (((size_t)0 * 8 + rt) * 8 + kx0) * 64 + lane;
    short8 ax[4];
#pragma unroll
    for (int i = 0; i < 4; i++) ax[i] = Ax[(size_t)i * 64];
#pragma unroll
    for (int i = 0; i < 4; i++) {
      xa0 = __builtin_amdgcn_mfma_f32_16x16x32_bf16(ax[i], bxw[i][0], xa0, 0, 0, 0);
      xa1 = __builtin_amdgcn_mfma_f32_16x16x32_bf16(ax[i], bxw[i][1], xa1, 0, 0, 0);
      xa2 = __builtin_amdgcn_mfma_f32_16x16x32_bf16(ax[i], bxw[i][2], xa2, 0, 0, 0);
      xa3 = __builtin_amdgcn_mfma_f32_16x16x32_bf16(ax[i], bxw[i][3], xa3, 0, 0, 0);
    }
  }

  if (w == 0) {  // leader wave polls group's 64 flags: one load per lane
    while (true) {
      unsigned int v = __hip_atomic_load(&fl[grp + lane], __ATOMIC_RELAXED,
                                         __HIP_MEMORY_SCOPE_AGENT);
      if (__all((int)(v >= 1u))) break;
    }
  }
  __syncthreads();
  asm volatile("" ::: "memory");

#pragma unroll 1
  for (int t = 0; t < 256; t++) {
    const unsigned short* hc = (t & 1) ? hb1 : hb0;
    unsigned short* hn = (t & 1) ? hb0 : hb1;

    // ---- h_t loads: relaxed agent (bypass stale L2, served at MALL)
    const unsigned short* Ahp = hc + ((size_t)(rt * 32 + kc0) * 64 + lane) * 8;
    unsigned long long hq[32];
#pragma unroll
    for (int i = 0; i < 16; i++) {
      hq[2 * i] = __hip_atomic_load((const unsigned long long*)(Ahp + (size_t)i * 512),
                                    __ATOMIC_RELAXED, __HIP_MEMORY_SCOPE_AGENT);
      hq[2 * i + 1] = __hip_atomic_load((const unsigned long long*)(Ahp + (size_t)i * 512 + 4),
                                        __ATOMIC_RELAXED, __HIP_MEMORY_SCOPE_AGENT);
    }
    // ---- x fragments for step t+1 (L2-hot; used at loop end)
    int tn = (t < 255) ? t + 1 : 255;
    const short8* Axn = (const short8*)xb + (((size_t)tn * 8 + rt) * 8 + kx0) * 64 + lane;
    short8 ax[4];
#pragma unroll
    for (int i = 0; i < 4; i++) ax[i] = Axn[(size_t)i * 64];

    // ---- h-part GEMM accumulates into the precomputed x-part acc
    floatx4 a0 = xa0, a1 = xa1, a2 = xa2, a3 = xa3;
#pragma unroll
    for (int kc = 0; kc < 16; kc++) {
      union { unsigned long long q[2]; short8 v; } u;
      u.q[0] = hq[2 * kc];
      u.q[1] = hq[2 * kc + 1];
      short8 av = u.v;
      short8 b0 = BL[(size_t)(kc * 4 + 0) * 64];
      short8 b1v = BL[(size_t)(kc * 4 + 1) * 64];
      short8 b2 = BL[(size_t)(kc * 4 + 2) * 64];
      short8 b3 = BL[(size_t)(kc * 4 + 3) * 64];
      a0 = __builtin_amdgcn_mfma_f32_16x16x32_bf16(av, b0, a0, 0, 0, 0);
      a1 = __builtin_amdgcn_mfma_f32_16x16x32_bf16(av, b1v, a1, 0, 0, 0);
      a2 = __builtin_amdgcn_mfma_f32_16x16x32_bf16(av, b2, a2, 0, 0, 0);
      a3 = __builtin_amdgcn_mfma_f32_16x16x32_bf16(av, b3, a3, 0, 0, 0);
    }

    // ---- gate partials -> LDS (C/D layout: col = lane&15, row = (lane>>4)*4+p)
    {
      int cl = lane & 15, q = lane >> 4;
#pragma unroll
      for (int p = 0; p < 4; p++) {
        int rrow = rt01 * 16 + q * 4 + p;
        xg[kh][0][rrow][cl] = a0[p];
        xg[kh][1][rrow][cl] = a1[p];
        xg[kh][2][rrow][cl] = a2[p];
        xg[kh][3][rrow][cl] = a3[p];
      }
    }
    __syncthreads();

    // ---- pointwise cell update: 2 adjacent cells/thread, packed 4-B h store
    {
      int rr = tid >> 3, n0 = (tid & 7) * 2;
      int r = rtq * 32 + rr;
      int rt_r = r >> 4, m = r & 15;
      unsigned int packed = 0;
#pragma unroll
      for (int u = 0; u < 2; u++) {
        int n = n0 + u;
        float pg = xg[0][0][rr][n] + xg[1][0][rr][n] + bb[0][n];
        float pi_ = xg[0][1][rr][n] + xg[1][1][rr][n] + bb[1][n];
        float pf = xg[0][2][rr][n] + xg[1][2][rr][n] + bb[2][n];
        float po = xg[0][3][rr][n] + xg[1][3][rr][n] + bb[3][n];
        float gg = tanh_fast(pg);
        float ii = sigm(pi_);
        float ff = sigm(pf);
        float oo = sigm(po);
        float cold = u ? c1 : c0;
        float cn = gg * ii + cold * ff;
        if (u) c1 = cn; else c0 = cn;
        float hv = tanh_fast(cn) * oo;
        packed |= ((unsigned int)f2bf(hv)) << (16 * u);
      }
      int j = jb * 16 + n0;
      size_t dst = ((size_t)(rt_r * 32 + (j >> 5)) * 64 + (((j >> 3) & 3) * 16 + m)) * 8 + (j & 7);
      __hip_atomic_store((unsigned int*)(hn + dst), packed, __ATOMIC_RELAXED,
                         __HIP_MEMORY_SCOPE_AGENT);
    }
    __syncthreads();  // drains vmcnt: h_{t+1} ack'd at MALL before flag store

    // ---- arrival flag (plain store, no RMW), then x-GEMM(t+1) fills the window
    if (tid == 0)
      __hip_atomic_store(&fl[grp + jb], (unsigned int)t + 2u, __ATOMIC_RELAXED,
                         __HIP_MEMORY_SCOPE_AGENT);

    xa0 = (floatx4){0.f, 0.f, 0.f, 0.f};
    xa1 = xa0; xa2 = xa0; xa3 = xa0;
#pragma unroll
    for (int i = 0; i < 4; i++) {
      xa0 = __builtin_amdgcn_mfma_f32_16x16x32_bf16(ax[i], bxw[i][0], xa0, 0, 0, 0);
      xa1 = __builtin_amdgcn_mfma_f32_16x16x32_bf16(ax[i], bxw[i][1], xa1, 0, 0, 0);
      xa2 = __builtin_amdgcn_mfma_f32_16x16x32_bf16(ax[i], bxw[i][2], xa2, 0, 0, 0);
      xa3 = __builtin_amdgcn_mfma_f32_16x16x32_bf16(ax[i], bxw[i][3], xa3, 0, 0, 0);
    }

    if (w == 0) {  // leader wave polls: all 64 group flags >= t+2
      unsigned int tgt = (unsigned int)t + 2u;
      while (true) {
        unsigned int v = __hip_atomic_load(&fl[grp + lane], __ATOMIC_RELAXED,
                                           __HIP_MEMORY_SCOPE_AGENT);
        if (__all((int)(v >= tgt))) break;
      }
    }
    __syncthreads();
    asm volatile("" ::: "memory");  // no hoisting of next-iter h loads above poll
  }
}

// ---------------------------------------------------------------------------
// Projection GEMM via MFMA: logits[128][1008] = h_T @ W_ph (+bias).
// Grid 504 = 63 col-tiles x 8 row-tiles; block = 4 waves splitting K=1024.
// Each block reads only its 16-col slice of Wph (64 KB) -> 32 MB total L3
// traffic vs 512 MB for the old per-row kernel.
// ---------------------------------------------------------------------------
__global__ __launch_bounds__(256) void proj_mfma(const unsigned short* __restrict__ hB,
                                                 const float* __restrict__ Wph,
                                                 const float* __restrict__ bp,
                                                 float* __restrict__ Lbuf) {
  __shared__ float pacc[4][16][17];
  const int tid = threadIdx.x;
  const int rt = blockIdx.x & 7;   // 16-row tile
  const int cb = blockIdx.x >> 3;  // 16-col tile (0..62)
  const int w = tid >> 6, lane = tid & 63;
  const int n = lane & 15, q = lane >> 4;
  const int j = cb * 16 + n;
  const bool jv = (j < C_);

  floatx4 acc = {0.f, 0.f, 0.f, 0.f};
  const short8* Ah = (const short8*)hB + ((size_t)rt * 32) * 64 + lane;
#pragma unroll
  for (int kq = 0; kq < 8; kq++) {
    int kc = w * 8 + kq;
    short8 a = Ah[(size_t)kc * 64];
    int k0 = kc * 32 + q * 8;
    unsigned int wb[4];
#pragma unroll
    for (int i = 0; i < 4; i++) {
      float fa = jv ? Wph[(size_t)(k0 + 2 * i) * C_ + j] : 0.f;
      float fb = jv ? Wph[(size_t)(k0 + 2 * i + 1) * C_ + j] : 0.f;
      wb[i] = (unsigned int)f2bf(fa) | ((unsigned int)f2bf(fb) << 16);
    }
    union { unsigned int u[4]; short8 v; } bu;
    bu.u[0] = wb[0]; bu.u[1] = wb[1]; bu.u[2] = wb[2]; bu.u[3] = wb[3];
    acc = __builtin_amdgcn_mfma_f32_16x16x32_bf16(a, bu.v, acc, 0, 0, 0);
  }
#pragma unroll
  for (int p = 0; p < 4; p++) pacc[w][q * 4 + p][n] = acc[p];
  __syncthreads();

  // reduce 4 K-quarters + bias, write logits
  {
    int r = tid >> 4, nn = tid & 15;
    int jj = cb * 16 + nn;
    float s = pacc[0][r][nn] + pacc[1][r][nn] + pacc[2][r][nn] + pacc[3][r][nn];
    s += (jj < C_) ? bp[jj] : 0.f;
    Lbuf[(size_t)(rt * 16 + r) * 1008 + jj] = s;
  }
}

// ---------------------------------------------------------------------------
// Row-wise log_softmax over precomputed logits.
// ---------------------------------------------------------------------------
__global__ __launch_bounds__(256) void softmax_k(const float* __restrict__ Lbuf,
                                                 float* __restrict__ out) {
  __shared__ float red[256];
  int row = blockIdx.x, tid = threadIdx.x;
  const float* Lr = Lbuf + (size_t)row * 1008;
  bool v3 = (tid + 768 < C_);
  float a0 = Lr[tid];
  float a1 = Lr[tid + 256];
  float a2 = Lr[tid + 512];
  float a3 = v3 ? Lr[tid + 768] : 0.f;

  float mx = fmaxf(fmaxf(a0, a1), a2);
  if (v3) mx = fmaxf(mx, a3);
  red[tid] = mx;
  __syncthreads();
  for (int s = 128; s > 0; s >>= 1) {
    if (tid < s) red[tid] = fmaxf(red[tid], red[tid + s]);
    __syncthreads();
  }
  float M = red[0];
  __syncthreads();
  float se = __expf(a0 - M) + __expf(a1 - M) + __expf(a2 - M);
  if (v3) se += __expf(a3 - M);
  red[tid] = se;
  __syncthreads();
  for (int s = 128; s > 0; s >>= 1) {
    if (tid < s) red[tid] += red[tid + s];
    __syncthreads();
  }
  float lse = M + logf(red[0]);
  out[(size_t)row * C_ + tid] = a0 - lse;
  out[(size_t)row * C_ + tid + 256] = a1 - lse;
  out[(size_t)row * C_ + tid + 512] = a2 - lse;
  if (v3) out[(size_t)row * C_ + tid + 768] = a3 - lse;
}

extern "C" void kernel_launch(void* const* d_in, const int* in_sizes, int n_in,
                              void* d_out, int out_size, void* d_ws, size_t ws_size,
                              hipStream_t stream) {
  const float* x   = (const float*)d_in[0];
  const float* Wgx = (const float*)d_in[1];
  const float* Wix = (const float*)d_in[2];
  const float* Wfx = (const float*)d_in[3];
  const float* Wox = (const float*)d_in[4];
  const float* Wgh = (const float*)d_in[5];
  const float* Wih = (const float*)d_in[6];
  const float* Wfh = (const float*)d_in[7];
  const float* Woh = (const float*)d_in[8];
  const float* Wph = (const float*)d_in[9];
  const float* bg  = (const float*)d_in[10];
  const float* bi  = (const float*)d_in[11];
  const float* bf  = (const float*)d_in[12];
  const float* bo  = (const float*)d_in[13];
  const float* bp  = (const float*)d_in[14];

  char* ws = (char*)d_ws;
  unsigned short* Wp = (unsigned short*)ws;                 // 10,485,760 B
  size_t off = 10485760;
  unsigned short* xb = (unsigned short*)(ws + off);         // 16 MB; reused as Lbuf
  float* Lbuf = (float*)xb;
  off += 16777216;
  unsigned short* h0 = (unsigned short*)(ws + off); off += 262144;
  unsigned short* h1 = (unsigned short*)(ws + off); off += 262144;
  unsigned int* fl = (unsigned int*)(ws + off); off += 4096;

  hipMemsetAsync(fl, 0, 4096, stream);  // reset flags each launch/replay

  pack_all<<<6656, 256, 0, stream>>>(Wgx, Wix, Wfx, Wox, Wgh, Wih, Wfh, Woh, Wp, x, xb);

  void* args[] = {(void*)&h0, (void*)&h1, (void*)&Wp, (void*)&xb,
                  (void*)&bg, (void*)&bi, (void*)&bf, (void*)&bo, (void*)&fl};
  hipError_t cerr = hipLaunchCooperativeKernel((void*)lstm_all, dim3(256), dim3(256),
                                               args, 0, stream);
  if (cerr != hipSuccess) {
    // Fallback: 256 blocks with ~146 KB LDS each force 1 block/CU -> co-resident
    lstm_all<<<256, 256, 0, stream>>>(h0, h1, Wp, xb, bg, bi, bf, bo, fl);
  }

  // after 256 steps the final h is in h0 (t=255 stores into hb0)
  proj_mfma<<<504, 256, 0, stream>>>(h0, Wph, bp, Lbuf);
  softmax_k<<<128, 256, 0, stream>>>(Lbuf, (float*)d_out);
}